// Round 13
// baseline (133.299 us; speedup 1.0000x reference)
//
#include <hip/hip_runtime.h>
#include <hip/hip_bf16.h>

#define N_NODES 65536
#define N_EDGES (N_NODES * 7)
#define NSEG    (N_NODES * 7)          // 458752
#define CAP     12
#define ZROW    65536                  // index of the all-zero row in xb

typedef short short8 __attribute__((ext_vector_type(8)));
typedef float f32x4  __attribute__((ext_vector_type(4)));
typedef float f32x16 __attribute__((ext_vector_type(16)));

// f32 -> bf16 via hardware cvt (compiler emits v_cvt_pk_bf16_f32 for pairs)
__device__ __forceinline__ unsigned short f2bf(float f) {
    return __builtin_bit_cast(unsigned short, (__bf16)f);
}
__device__ __forceinline__ unsigned pack2(float lo, float hi) {
    return (unsigned)f2bf(lo) | ((unsigned)f2bf(hi) << 16);
}
// bf16 pair unpack from dword
__device__ __forceinline__ float bflo(unsigned d) { return __uint_as_float(d << 16); }
__device__ __forceinline__ float bfhi(unsigned d) { return __uint_as_float(d & 0xffff0000u); }

// ---------------- fused prep: edge scatter + x->bf16 + W->B-frag ----------------
// seg32[seg] = cnt(7b at bit 0) | typecount_u(5b at bit 7+5u). Pre-zeroed by memset.
// wb: B-fragments for mfma_f32_32x32x16_bf16, K padded to 144 per type:
//   wb[(((t*9+kc)*4+cg)*64 + lane)*8 + j] = W[t*133 + kc*16 + (lane>>5)*8 + j][cg*32 + (lane&31)]
__global__ __launch_bounds__(256) void k_big(const float* __restrict__ x,
                                             const int* __restrict__ eidx,
                                             const int* __restrict__ etype,
                                             const int* __restrict__ ntype,
                                             const float* __restrict__ W,
                                             unsigned short* __restrict__ xb,
                                             unsigned short* __restrict__ wb,
                                             unsigned* __restrict__ seg32,
                                             unsigned short* __restrict__ scol) {
    int i = blockIdx.x * 256 + threadIdx.x;     // grid 4096*256 = 1048576

    // edge scatter (issue first: its random loads overlap the streaming below)
    if (i < N_EDGES) {
        int t = etype[i];
        if (t < 6) {                    // type-6 slot overwritten by self-loop
            int r = eidx[i];
            int c = eidx[N_EDGES + i];
            int u = ntype[c];
            unsigned seg = (unsigned)r * 7u + (unsigned)t;
            unsigned inc = 1u | (1u << (7 + 5 * u));
            unsigned old = atomicAdd(&seg32[seg], inc);
            unsigned slot = old & 0x7fu;
            if (slot < CAP) scol[seg * CAP + slot] = (unsigned short)c;
        }
    }

    // x -> bf16 rows
    {
        int row = i >> 4, mm = i & 15;
        const f32x4* p = reinterpret_cast<const f32x4*>(x + (size_t)row * 128 + mm * 8);
        f32x4 v0 = p[0], v1 = p[1];
        uint4 w;
        w.x = pack2(v0[0], v0[1]); w.y = pack2(v0[2], v0[3]);
        w.z = pack2(v1[0], v1[1]); w.w = pack2(v1[2], v1[3]);
        reinterpret_cast<uint4*>(xb)[i] = w;
    }

    // zero row (gather fallback target)
    if (i < 16) reinterpret_cast<uint4*>(xb + (size_t)ZROW * 128)[i] = (uint4){0u, 0u, 0u, 0u};

    // W -> bf16 B-fragment order (32x32x16), 129024 elements
    if (i < 129024) {
        int j    = i & 7;
        int lane = (i >> 3) & 63;
        int cg   = (i >> 9) & 3;
        int tkc  = i >> 11;             // 0..62
        int kc   = tkc % 9;
        int t    = tkc / 9;
        int k = kc * 16 + ((lane >> 5) << 3) + j;
        int c = (cg << 5) + (lane & 31);
        float v = (k < 133) ? W[(t * 133 + k) * 128 + c] : 0.0f;
        wb[i] = f2bf(v);
    }
}

// ---------------- main fused kernel: zero-LDS, zero-barrier ----------------
// 1 wave (64 threads) per block, M=32 rows. Lane l: row r=l&31, k-half h=l>>5.
// Gather builds the 32x32x16 A-fragment DIRECTLY in registers (lane loads 16B
// chunks of its row's neighbors, means in f32, packs bf16). B streams from L2
// in fragment order. acc = 4 col-groups x f32x16 = 64 VGPR. No LDS, no syncs.
__global__ __launch_bounds__(64, 4) void k_main(const unsigned short* __restrict__ xb,
                                                const int* __restrict__ ntype,
                                                const unsigned* __restrict__ seg32,
                                                const unsigned short* __restrict__ scol,
                                                const unsigned short* __restrict__ wb,
                                                float* __restrict__ out) {
    const int lane = threadIdx.x;       // 0..63
    const int r    = lane & 31;
    const int h    = lane >> 5;         // k-half within 16-k chunk
    const int n0   = blockIdx.x * 32;
    const int n    = n0 + r;
    const int choff = h * 8;            // shorts offset inside a 16-k chunk

    const int ntS = ntype[n];

    f32x16 acc[4];
    #pragma unroll
    for (int cg = 0; cg < 4; ++cg)
        #pragma unroll
        for (int q = 0; q < 16; ++q) acc[cg][q] = 0.f;

    #pragma unroll 1
    for (int t = 0; t < 7; ++t) {
        unsigned svt = 0, cnt, cA, cB;
        uint2 q2t = {0u, 0u};
        if (t < 6) {
            svt = seg32[n * 7 + t];
            cnt = svt & 0x7fu;
            q2t = *reinterpret_cast<const uint2*>(scol + ((size_t)n * 7 + t) * CAP);
            cA = (cnt >= 1u) ? (q2t.x & 0xffffu) : (unsigned)ZROW;
            cB = (cnt >= 2u) ? (q2t.x >> 16)     : (unsigned)ZROW;
        } else {                        // self-loop slot: own row, "count 1"
            cnt = 1u; cA = (unsigned)n; cB = (unsigned)ZROW;
        }
        const float inv = (cnt > 1u) ? __builtin_amdgcn_rcpf((float)cnt) : 1.0f;
        const unsigned ce = (cnt < (unsigned)CAP) ? cnt : (unsigned)CAP;
        const size_t segbase = ((size_t)n * 7 + t) * CAP;

        // ---- kc = 0..7: feature chunks straight from xb ----
        #pragma unroll
        for (int kc = 0; kc < 8; ++kc) {
            uint4 a4 = *reinterpret_cast<const uint4*>(
                xb + (size_t)cA * 128 + kc * 16 + choff);
            uint4 w;
            if (cnt <= 1u) {
                w = a4;                 // cnt=0 -> ZROW zeros; cnt=1 -> exact copy
            } else {
                uint4 b4 = *reinterpret_cast<const uint4*>(
                    xb + (size_t)cB * 128 + kc * 16 + choff);
                float f[8];
                f[0] = bflo(a4.x) + bflo(b4.x); f[1] = bfhi(a4.x) + bfhi(b4.x);
                f[2] = bflo(a4.y) + bflo(b4.y); f[3] = bfhi(a4.y) + bfhi(b4.y);
                f[4] = bflo(a4.z) + bflo(b4.z); f[5] = bfhi(a4.z) + bfhi(b4.z);
                f[6] = bflo(a4.w) + bflo(b4.w); f[7] = bfhi(a4.w) + bfhi(b4.w);
                if (cnt >= 3u) {        // rare tail (~8% of segments)
                    for (unsigned e = 2; e < ce; ++e) {
                        unsigned c = scol[segbase + e];
                        uint4 v4 = *reinterpret_cast<const uint4*>(
                            xb + (size_t)c * 128 + kc * 16 + choff);
                        f[0] += bflo(v4.x); f[1] += bfhi(v4.x);
                        f[2] += bflo(v4.y); f[3] += bfhi(v4.y);
                        f[4] += bflo(v4.z); f[5] += bfhi(v4.z);
                        f[6] += bflo(v4.w); f[7] += bfhi(v4.w);
                    }
                }
                w.x = pack2(f[0] * inv, f[1] * inv);
                w.y = pack2(f[2] * inv, f[3] * inv);
                w.z = pack2(f[4] * inv, f[5] * inv);
                w.w = pack2(f[6] * inv, f[7] * inv);
            }
            short8 av = *reinterpret_cast<const short8*>(&w);
            #pragma unroll
            for (int cg = 0; cg < 4; ++cg) {
                short8 bv = *reinterpret_cast<const short8*>(
                    wb + ((((t * 9 + kc) * 4 + cg) << 6) + lane) * 8);
                acc[cg] = __builtin_amdgcn_mfma_f32_32x32x16_bf16(av, bv, acc[cg], 0, 0, 0);
            }
        }

        // ---- kc = 8: one-hot chunk (k 128..143; data only in h=0, j=0..4) ----
        {
            uint4 w = {0u, 0u, 0u, 0u};
            if (h == 0) {
                float g0, g1, g2, g3, g4;
                if (t < 6) {
                    g0 = (float)((svt >> 7)  & 31u) * inv;
                    g1 = (float)((svt >> 12) & 31u) * inv;
                    g2 = (float)((svt >> 17) & 31u) * inv;
                    g3 = (float)((svt >> 22) & 31u) * inv;
                    g4 = (float)((svt >> 27) & 31u) * inv;
                } else {
                    g0 = (ntS == 0) ? 1.f : 0.f; g1 = (ntS == 1) ? 1.f : 0.f;
                    g2 = (ntS == 2) ? 1.f : 0.f; g3 = (ntS == 3) ? 1.f : 0.f;
                    g4 = (ntS == 4) ? 1.f : 0.f;
                }
                w.x = pack2(g0, g1); w.y = pack2(g2, g3); w.z = pack2(g4, 0.f);
            }
            short8 av = *reinterpret_cast<const short8*>(&w);
            #pragma unroll
            for (int cg = 0; cg < 4; ++cg) {
                short8 bv = *reinterpret_cast<const short8*>(
                    wb + ((((t * 9 + 8) * 4 + cg) << 6) + lane) * 8);
                acc[cg] = __builtin_amdgcn_mfma_f32_32x32x16_bf16(av, bv, acc[cg], 0, 0, 0);
            }
        }
    }

    // epilogue: 32x32 C/D layout (HW-verified): col = lane&31,
    // row = (reg&3) + 8*(reg>>2) + 4*(lane>>5)
    const int col = lane & 31;
    #pragma unroll
    for (int cg = 0; cg < 4; ++cg) {
        #pragma unroll
        for (int reg = 0; reg < 16; ++reg) {
            const int row = (reg & 3) + 8 * (reg >> 2) + 4 * h;
            out[(size_t)(n0 + row) * 128 + (cg << 5) + col] = acc[cg][reg];
        }
    }
}

// ---------------- launch ----------------

extern "C" void kernel_launch(void* const* d_in, const int* in_sizes, int n_in,
                              void* d_out, int out_size, void* d_ws, size_t ws_size,
                              hipStream_t stream) {
    const float* x     = (const float*)d_in[0];
    const int*   eidx  = (const int*)d_in[1];
    const int*   etype = (const int*)d_in[2];
    const int*   ntype = (const int*)d_in[3];
    const float* W     = (const float*)d_in[4];
    float* out = (float*)d_out;

    // ws: xb (65537 rows) 16777472 | wb 258048 | seg32 1835008 | scol 11010048
    unsigned short* xb    = (unsigned short*)d_ws;
    unsigned short* wb    = (unsigned short*)((char*)d_ws + 16777472);
    unsigned*       seg32 = (unsigned*)((char*)d_ws + 17035520);
    unsigned short* scol  = (unsigned short*)((char*)d_ws + 18870528);

    hipMemsetAsync(seg32, 0, NSEG * sizeof(unsigned), stream);
    k_big <<<4096,         256, 0, stream>>>(x, eidx, etype, ntype, W, xb, wb, seg32, scol);
    k_main<<<N_NODES / 32,  64, 0, stream>>>(xb, ntype, seg32, scol, wb, out);
}

// Round 14
// 106.474 us; speedup vs baseline: 1.2519x; 1.2519x over previous
//
#include <hip/hip_runtime.h>
#include <hip/hip_bf16.h>

#define N_NODES 65536
#define N_EDGES (N_NODES * 7)
#define NSEG    (N_NODES * 7)          // 458752
#define CAP     12
#define ZROW    65536                  // index of the all-zero row in xb

typedef short short8 __attribute__((ext_vector_type(8)));
typedef float f32x4  __attribute__((ext_vector_type(4)));
typedef float f32x16 __attribute__((ext_vector_type(16)));

// f32 -> bf16 via hardware cvt (compiler emits v_cvt_pk_bf16_f32 for pairs)
__device__ __forceinline__ unsigned short f2bf(float f) {
    return __builtin_bit_cast(unsigned short, (__bf16)f);
}
__device__ __forceinline__ unsigned pack2(float lo, float hi) {
    return (unsigned)f2bf(lo) | ((unsigned)f2bf(hi) << 16);
}
// bf16 pair unpack from dword
__device__ __forceinline__ float bflo(unsigned d) { return __uint_as_float(d << 16); }
__device__ __forceinline__ float bfhi(unsigned d) { return __uint_as_float(d & 0xffff0000u); }

// ---------------- fused prep: edge scatter + x->bf16 + W->B-frag ----------------
// seg32[seg] = cnt(7b at bit 0) | typecount_u(5b at bit 7+5u). Pre-zeroed by memset.
// wb: B-fragments for mfma_f32_32x32x16_bf16, K padded to 144 per type:
//   wb[(((t*9+kc)*4+cg)*64 + lane)*8 + j] = W[t*133 + kc*16 + (lane>>5)*8 + j][cg*32 + (lane&31)]
__global__ __launch_bounds__(256) void k_big(const float* __restrict__ x,
                                             const int* __restrict__ eidx,
                                             const int* __restrict__ etype,
                                             const int* __restrict__ ntype,
                                             const float* __restrict__ W,
                                             unsigned short* __restrict__ xb,
                                             unsigned short* __restrict__ wb,
                                             unsigned* __restrict__ seg32,
                                             unsigned short* __restrict__ scol) {
    int i = blockIdx.x * 256 + threadIdx.x;     // grid 4096*256 = 1048576

    // edge scatter (issue first: its random loads overlap the streaming below)
    if (i < N_EDGES) {
        int t = etype[i];
        if (t < 6) {                    // type-6 slot overwritten by self-loop
            int r = eidx[i];
            int c = eidx[N_EDGES + i];
            int u = ntype[c];
            unsigned seg = (unsigned)r * 7u + (unsigned)t;
            unsigned inc = 1u | (1u << (7 + 5 * u));
            unsigned old = atomicAdd(&seg32[seg], inc);
            unsigned slot = old & 0x7fu;
            if (slot < CAP) scol[seg * CAP + slot] = (unsigned short)c;
        }
    }

    // x -> bf16 rows
    {
        int row = i >> 4, mm = i & 15;
        const f32x4* p = reinterpret_cast<const f32x4*>(x + (size_t)row * 128 + mm * 8);
        f32x4 v0 = p[0], v1 = p[1];
        uint4 w;
        w.x = pack2(v0[0], v0[1]); w.y = pack2(v0[2], v0[3]);
        w.z = pack2(v1[0], v1[1]); w.w = pack2(v1[2], v1[3]);
        reinterpret_cast<uint4*>(xb)[i] = w;
    }

    // zero row (gather fallback target)
    if (i < 16) reinterpret_cast<uint4*>(xb + (size_t)ZROW * 128)[i] = (uint4){0u, 0u, 0u, 0u};

    // W -> bf16 B-fragment order (32x32x16), 129024 elements
    if (i < 129024) {
        int j    = i & 7;
        int lane = (i >> 3) & 63;
        int cg   = (i >> 9) & 3;
        int tkc  = i >> 11;             // 0..62
        int kc   = tkc % 9;
        int t    = tkc / 9;
        int k = kc * 16 + ((lane >> 5) << 3) + j;
        int c = (cg << 5) + (lane & 31);
        float v = (k < 133) ? W[(t * 133 + k) * 128 + c] : 0.0f;
        wb[i] = f2bf(v);
    }
}

// ---------------- main fused kernel: zero-LDS, zero-barrier, branchless ----------------
// 1 wave per block, M=32 rows. Lane l: row r=l&31, k-half h=l>>5. Gather builds
// the 32x32x16 A-fragment directly in registers. BRANCHLESS hot path: slots
// e0..e3 always load (ZROW address fallback, bit-exact); tail only for cnt>=5.
// launch_bounds(64,2) -> 256-VGPR cap so ~16+ loads stay in flight (R13 had a
// 60-VGPR squeeze that fully serialized the memory pipeline).
__global__ __launch_bounds__(64, 2) void k_main(const unsigned short* __restrict__ xb,
                                                const int* __restrict__ ntype,
                                                const unsigned* __restrict__ seg32,
                                                const unsigned short* __restrict__ scol,
                                                const unsigned short* __restrict__ wb,
                                                float* __restrict__ out) {
    const int lane = threadIdx.x;       // 0..63
    const int r    = lane & 31;
    const int h    = lane >> 5;         // k-half within 16-k chunk
    const int n0   = blockIdx.x * 32;
    const int n    = n0 + r;
    const int choff = h * 8;            // shorts offset inside a 16-k chunk

    const int ntS = ntype[n];

    // hoisted per-type descriptors (12 independent loads, all in flight)
    unsigned svv[6];
    uint2 q2v[6];
    #pragma unroll
    for (int t = 0; t < 6; ++t) {
        svv[t] = seg32[n * 7 + t];
        q2v[t] = *reinterpret_cast<const uint2*>(scol + ((size_t)n * 7 + t) * CAP);
    }

    f32x16 acc[4];
    #pragma unroll
    for (int cg = 0; cg < 4; ++cg)
        #pragma unroll
        for (int q = 0; q < 16; ++q) acc[cg][q] = 0.f;

    #pragma unroll 2
    for (int t = 0; t < 6; ++t) {
        const unsigned svt = svv[t];
        const unsigned cnt = svt & 0x7fu;
        const float inv = (cnt > 1u) ? __builtin_amdgcn_rcpf((float)cnt) : 1.0f;
        const unsigned ce = (cnt < (unsigned)CAP) ? cnt : (unsigned)CAP;
        const unsigned c0 = (cnt >= 1u) ? (q2v[t].x & 0xffffu) : (unsigned)ZROW;
        const unsigned c1 = (cnt >= 2u) ? (q2v[t].x >> 16)     : (unsigned)ZROW;
        const unsigned c2 = (cnt >= 3u) ? (q2v[t].y & 0xffffu) : (unsigned)ZROW;
        const unsigned c3 = (cnt >= 4u) ? (q2v[t].y >> 16)     : (unsigned)ZROW;
        const size_t segbase = ((size_t)n * 7 + t) * CAP;
        const unsigned short* p0 = xb + (size_t)c0 * 128 + choff;
        const unsigned short* p1 = xb + (size_t)c1 * 128 + choff;
        const unsigned short* p2 = xb + (size_t)c2 * 128 + choff;
        const unsigned short* p3 = xb + (size_t)c3 * 128 + choff;

        // ---- kc = 0..7: feature chunks, branchless 4-slot mean ----
        #pragma unroll
        for (int kc = 0; kc < 8; ++kc) {
            uint4 a4 = *reinterpret_cast<const uint4*>(p0 + kc * 16);
            uint4 b4 = *reinterpret_cast<const uint4*>(p1 + kc * 16);
            uint4 e4 = *reinterpret_cast<const uint4*>(p2 + kc * 16);
            uint4 d4 = *reinterpret_cast<const uint4*>(p3 + kc * 16);
            float f[8];
            f[0] = (bflo(a4.x) + bflo(b4.x)) + (bflo(e4.x) + bflo(d4.x));
            f[1] = (bfhi(a4.x) + bfhi(b4.x)) + (bfhi(e4.x) + bfhi(d4.x));
            f[2] = (bflo(a4.y) + bflo(b4.y)) + (bflo(e4.y) + bflo(d4.y));
            f[3] = (bfhi(a4.y) + bfhi(b4.y)) + (bfhi(e4.y) + bfhi(d4.y));
            f[4] = (bflo(a4.z) + bflo(b4.z)) + (bflo(e4.z) + bflo(d4.z));
            f[5] = (bfhi(a4.z) + bfhi(b4.z)) + (bfhi(e4.z) + bfhi(d4.z));
            f[6] = (bflo(a4.w) + bflo(b4.w)) + (bflo(e4.w) + bflo(d4.w));
            f[7] = (bfhi(a4.w) + bfhi(b4.w)) + (bfhi(e4.w) + bfhi(d4.w));
            if (cnt > 4u) {             // rare tail (~0.4% of segments)
                for (unsigned e = 4; e < ce; ++e) {
                    unsigned c = scol[segbase + e];
                    uint4 v4 = *reinterpret_cast<const uint4*>(
                        xb + (size_t)c * 128 + kc * 16 + choff);
                    f[0] += bflo(v4.x); f[1] += bfhi(v4.x);
                    f[2] += bflo(v4.y); f[3] += bfhi(v4.y);
                    f[4] += bflo(v4.z); f[5] += bfhi(v4.z);
                    f[6] += bflo(v4.w); f[7] += bfhi(v4.w);
                }
            }
            uint4 w;
            w.x = pack2(f[0] * inv, f[1] * inv);
            w.y = pack2(f[2] * inv, f[3] * inv);
            w.z = pack2(f[4] * inv, f[5] * inv);
            w.w = pack2(f[6] * inv, f[7] * inv);
            short8 av = *reinterpret_cast<const short8*>(&w);
            #pragma unroll
            for (int cg = 0; cg < 4; ++cg) {
                short8 bv = *reinterpret_cast<const short8*>(
                    wb + ((((t * 9 + kc) * 4 + cg) << 6) + lane) * 8);
                acc[cg] = __builtin_amdgcn_mfma_f32_32x32x16_bf16(av, bv, acc[cg], 0, 0, 0);
            }
        }

        // ---- kc = 8: one-hot chunk (k 128..143; data only in h=0, j=0..4) ----
        {
            uint4 w = {0u, 0u, 0u, 0u};
            if (h == 0) {
                float g0 = (float)((svt >> 7)  & 31u) * inv;
                float g1 = (float)((svt >> 12) & 31u) * inv;
                float g2 = (float)((svt >> 17) & 31u) * inv;
                float g3 = (float)((svt >> 22) & 31u) * inv;
                float g4 = (float)((svt >> 27) & 31u) * inv;
                w.x = pack2(g0, g1); w.y = pack2(g2, g3); w.z = pack2(g4, 0.f);
            }
            short8 av = *reinterpret_cast<const short8*>(&w);
            #pragma unroll
            for (int cg = 0; cg < 4; ++cg) {
                short8 bv = *reinterpret_cast<const short8*>(
                    wb + ((((t * 9 + 8) * 4 + cg) << 6) + lane) * 8);
                acc[cg] = __builtin_amdgcn_mfma_f32_32x32x16_bf16(av, bv, acc[cg], 0, 0, 0);
            }
        }
    }

    // ---- t = 6: self-loop slot (straight copy of own row + own one-hot) ----
    {
        const unsigned short* ps = xb + (size_t)n * 128 + choff;
        #pragma unroll
        for (int kc = 0; kc < 8; ++kc) {
            uint4 a4 = *reinterpret_cast<const uint4*>(ps + kc * 16);
            short8 av = *reinterpret_cast<const short8*>(&a4);
            #pragma unroll
            for (int cg = 0; cg < 4; ++cg) {
                short8 bv = *reinterpret_cast<const short8*>(
                    wb + ((((6 * 9 + kc) * 4 + cg) << 6) + lane) * 8);
                acc[cg] = __builtin_amdgcn_mfma_f32_32x32x16_bf16(av, bv, acc[cg], 0, 0, 0);
            }
        }
        uint4 w = {0u, 0u, 0u, 0u};
        if (h == 0) {
            w.x = pack2((float)(ntS == 0), (float)(ntS == 1));
            w.y = pack2((float)(ntS == 2), (float)(ntS == 3));
            w.z = pack2((float)(ntS == 4), 0.f);
        }
        short8 av = *reinterpret_cast<const short8*>(&w);
        #pragma unroll
        for (int cg = 0; cg < 4; ++cg) {
            short8 bv = *reinterpret_cast<const short8*>(
                wb + ((((6 * 9 + 8) * 4 + cg) << 6) + lane) * 8);
            acc[cg] = __builtin_amdgcn_mfma_f32_32x32x16_bf16(av, bv, acc[cg], 0, 0, 0);
        }
    }

    // epilogue: 32x32 C/D layout (HW-verified): col = lane&31,
    // row = (reg&3) + 8*(reg>>2) + 4*(lane>>5)
    const int col = lane & 31;
    #pragma unroll
    for (int cg = 0; cg < 4; ++cg) {
        #pragma unroll
        for (int reg = 0; reg < 16; ++reg) {
            const int row = (reg & 3) + 8 * (reg >> 2) + 4 * h;
            out[(size_t)(n0 + row) * 128 + (cg << 5) + col] = acc[cg][reg];
        }
    }
}

// ---------------- launch ----------------

extern "C" void kernel_launch(void* const* d_in, const int* in_sizes, int n_in,
                              void* d_out, int out_size, void* d_ws, size_t ws_size,
                              hipStream_t stream) {
    const float* x     = (const float*)d_in[0];
    const int*   eidx  = (const int*)d_in[1];
    const int*   etype = (const int*)d_in[2];
    const int*   ntype = (const int*)d_in[3];
    const float* W     = (const float*)d_in[4];
    float* out = (float*)d_out;

    // ws: xb (65537 rows) 16777472 | wb 258048 | seg32 1835008 | scol 11010048
    unsigned short* xb    = (unsigned short*)d_ws;
    unsigned short* wb    = (unsigned short*)((char*)d_ws + 16777472);
    unsigned*       seg32 = (unsigned*)((char*)d_ws + 17035520);
    unsigned short* scol  = (unsigned short*)((char*)d_ws + 18870528);

    hipMemsetAsync(seg32, 0, NSEG * sizeof(unsigned), stream);
    k_big <<<4096,         256, 0, stream>>>(x, eidx, etype, ntype, W, xb, wb, seg32, scol);
    k_main<<<N_NODES / 32,  64, 0, stream>>>(xb, ntype, seg32, scol, wb, out);
}

// Round 15
// 84.070 us; speedup vs baseline: 1.5856x; 1.2665x over previous
//
#include <hip/hip_runtime.h>
#include <hip/hip_bf16.h>

#define N_NODES 65536
#define N_EDGES (N_NODES * 7)
#define NSEG    (N_NODES * 7)          // 458752
#define CAP     12
#define ZROW    65536                  // index of the all-zero row in xb

typedef short short8 __attribute__((ext_vector_type(8)));
typedef float f32x4  __attribute__((ext_vector_type(4)));

// f32 -> bf16 via hardware cvt (compiler emits v_cvt_pk_bf16_f32 for pairs)
__device__ __forceinline__ unsigned short f2bf(float f) {
    return __builtin_bit_cast(unsigned short, (__bf16)f);
}
__device__ __forceinline__ unsigned pack2(float lo, float hi) {
    return (unsigned)f2bf(lo) | ((unsigned)f2bf(hi) << 16);
}
// bf16 pair unpack from dword
__device__ __forceinline__ float bflo(unsigned d) { return __uint_as_float(d << 16); }
__device__ __forceinline__ float bfhi(unsigned d) { return __uint_as_float(d & 0xffff0000u); }

// ---------------- fused prep: edge scatter + x->bf16 + W->B-frag ----------------
// seg32[seg] = cnt(7b at bit 0) | typecount_u(5b at bit 7+5u). Pre-zeroed by memset.
__global__ __launch_bounds__(256) void k_big(const float* __restrict__ x,
                                             const int* __restrict__ eidx,
                                             const int* __restrict__ etype,
                                             const int* __restrict__ ntype,
                                             const float* __restrict__ W,
                                             unsigned short* __restrict__ xb,
                                             unsigned short* __restrict__ wb,
                                             unsigned* __restrict__ seg32,
                                             unsigned short* __restrict__ scol) {
    int i = blockIdx.x * 256 + threadIdx.x;     // grid 4096*256 = 1048576

    // edge scatter (issue first: its random loads overlap the streaming below)
    if (i < N_EDGES) {
        int t = etype[i];
        if (t < 6) {                    // type-6 slot overwritten by self-loop
            int r = eidx[i];
            int c = eidx[N_EDGES + i];
            int u = ntype[c];
            unsigned seg = (unsigned)r * 7u + (unsigned)t;
            unsigned inc = 1u | (1u << (7 + 5 * u));
            unsigned old = atomicAdd(&seg32[seg], inc);
            unsigned slot = old & 0x7fu;
            if (slot < CAP) scol[seg * CAP + slot] = (unsigned short)c;
        }
    }

    // x -> bf16 rows
    {
        int row = i >> 4, mm = i & 15;
        const f32x4* p = reinterpret_cast<const f32x4*>(x + (size_t)row * 128 + mm * 8);
        f32x4 v0 = p[0], v1 = p[1];
        uint4 w;
        w.x = pack2(v0[0], v0[1]); w.y = pack2(v0[2], v0[3]);
        w.z = pack2(v1[0], v1[1]); w.w = pack2(v1[2], v1[3]);
        reinterpret_cast<uint4*>(xb)[i] = w;
    }

    // zero row (gather fallback target)
    if (i < 16) reinterpret_cast<uint4*>(xb + (size_t)ZROW * 128)[i] = (uint4){0u, 0u, 0u, 0u};

    // W -> bf16 B-fragment order (16x16x32): wb[(((t*5+kc)*8+cb)*64+lane)*8+j]
    if (i < 143360) {
        int j    = i & 7;
        int lane = (i >> 3) & 63;
        int cb   = (i >> 9) & 7;
        int tkc  = i >> 12;
        int kc   = tkc % 5;
        int t    = tkc / 5;
        int k = kc * 32 + ((lane >> 4) << 3) + j;
        int c = cb * 16 + (lane & 15);
        float v = (k < 133) ? W[(t * 133 + k) * 128 + c] : 0.0f;
        wb[i] = f2bf(v);
    }
}

// ---------------- main fused kernel: producer/consumer wave split ----------------
// 512 threads, 32 rows/block. Waves 0-3 = builders (8 thr/row x 16 ch), waves
// 4-7 = consumers. Ring of 2 LDS tile slots (21.5 KB). Phase t: consumers
// marathon tile t (slot t&1) while builders gather tile t+1 (slot (t+1)&1) --
// gather latency hides under MFMA within the block. Consumer = (2 strips x
// 2 cb): A-frag read once, used twice -> A-LDS traffic halved vs R9; B-frags
// still read exactly once per block. No gather regs live across phases except
// the 18-VGPR seg/q2 descriptors (R8 spill lesson).
__global__ __launch_bounds__(512, 6) void k_main(const unsigned short* __restrict__ xb,
                                                 const int* __restrict__ ntype,
                                                 const unsigned* __restrict__ seg32,
                                                 const unsigned short* __restrict__ scol,
                                                 const unsigned short* __restrict__ wb,
                                                 float* __restrict__ out) {
    __shared__ unsigned short sA[2][32][168];   // 21504 B

    const int tid  = threadIdx.x;
    const int lane = tid & 63;
    const int wid  = tid >> 6;
    const int n0   = blockIdx.x * 32;
    const bool consumer = (wid >= 4);

    // zero pad shorts 136..159 of all 64 slot-rows (3 uint4 each), once
    if (tid < 192) {
        int j = tid % 3, sr = tid / 3;          // sr 0..63
        *reinterpret_cast<uint4*>(&sA[sr >> 5][sr & 31][136 + j * 8]) =
            (uint4){0u, 0u, 0u, 0u};
    }

    // ---------------- builder state (waves 0-3; tid 0..255) ----------------
    const int r = (tid >> 3) & 31;      // row 0..31
    const int m = tid & 7;              // 16-channel chunk
    const int n = n0 + r;
    unsigned sv[6]; uint2 q2[6]; int ntS = 0;
    if (!consumer) {
        #pragma unroll
        for (int t = 0; t < 6; ++t) {
            sv[t] = seg32[n * 7 + t];
            q2[t] = *reinterpret_cast<const uint2*>(scol + ((size_t)n * 7 + t) * CAP);
        }
        ntS = ntype[n];
    }

    // add one neighbor row's 16 channels into f[16]
    auto addrow = [&](float* f, unsigned col) {
        const uint4* p = reinterpret_cast<const uint4*>(xb + (size_t)col * 128 + m * 16);
        uint4 u0 = p[0], u1 = p[1];
        f[0] += bflo(u0.x); f[1] += bfhi(u0.x); f[2]  += bflo(u0.y); f[3]  += bfhi(u0.y);
        f[4] += bflo(u0.z); f[5] += bfhi(u0.z); f[6]  += bflo(u0.w); f[7]  += bfhi(u0.w);
        f[8] += bflo(u1.x); f[9] += bfhi(u1.x); f[10] += bflo(u1.y); f[11] += bfhi(u1.y);
        f[12]+= bflo(u1.z); f[13]+= bfhi(u1.z); f[14] += bflo(u1.w); f[15] += bfhi(u1.w);
    };

    auto build_tile = [&](int t, int slot) {
        const unsigned svt = sv[t];
        const unsigned cnt = svt & 0x7fu;
        const float inv = (cnt > 1u) ? __builtin_amdgcn_rcpf((float)cnt) : 1.0f;
        unsigned c0 = (cnt >= 1u) ? (q2[t].x & 0xffffu) : (unsigned)ZROW;
        unsigned c1 = (cnt >= 2u) ? (q2[t].x >> 16)     : (unsigned)ZROW;
        const uint4* p0 = reinterpret_cast<const uint4*>(xb + (size_t)c0 * 128 + m * 16);
        const uint4* p1 = reinterpret_cast<const uint4*>(xb + (size_t)c1 * 128 + m * 16);
        uint4 a0 = p0[0], a1 = p0[1];
        uint4 b0 = p1[0], b1 = p1[1];
        uint4 w0, w1;
        if (cnt <= 1u) {
            w0 = a0; w1 = a1;               // cnt=0 -> ZROW zeros; cnt=1 -> exact copy
        } else {
            float f[16];
            f[0] = bflo(a0.x)+bflo(b0.x); f[1] = bfhi(a0.x)+bfhi(b0.x);
            f[2] = bflo(a0.y)+bflo(b0.y); f[3] = bfhi(a0.y)+bfhi(b0.y);
            f[4] = bflo(a0.z)+bflo(b0.z); f[5] = bfhi(a0.z)+bfhi(b0.z);
            f[6] = bflo(a0.w)+bflo(b0.w); f[7] = bfhi(a0.w)+bfhi(b0.w);
            f[8] = bflo(a1.x)+bflo(b1.x); f[9] = bfhi(a1.x)+bfhi(b1.x);
            f[10]= bflo(a1.y)+bflo(b1.y); f[11]= bfhi(a1.y)+bfhi(b1.y);
            f[12]= bflo(a1.z)+bflo(b1.z); f[13]= bfhi(a1.z)+bfhi(b1.z);
            f[14]= bflo(a1.w)+bflo(b1.w); f[15]= bfhi(a1.w)+bfhi(b1.w);
            if (cnt >= 3u) {                // rare tail (~8% of segments)
                const unsigned ce = (cnt < (unsigned)CAP) ? cnt : (unsigned)CAP;
                addrow(f, q2[t].y & 0xffffu);
                if (ce >= 4u) {
                    addrow(f, q2[t].y >> 16);
                    const size_t segbase = ((size_t)n * 7 + t) * CAP;
                    for (unsigned e = 4; e < ce; ++e)
                        addrow(f, (unsigned)scol[segbase + e]);
                }
            }
            w0.x = pack2(f[0]*inv,  f[1]*inv);  w0.y = pack2(f[2]*inv,  f[3]*inv);
            w0.z = pack2(f[4]*inv,  f[5]*inv);  w0.w = pack2(f[6]*inv,  f[7]*inv);
            w1.x = pack2(f[8]*inv,  f[9]*inv);  w1.y = pack2(f[10]*inv, f[11]*inv);
            w1.z = pack2(f[12]*inv, f[13]*inv); w1.w = pack2(f[14]*inv, f[15]*inv);
        }
        uint4* dst = reinterpret_cast<uint4*>(&sA[slot][r][m * 16]);
        dst[0] = w0;
        dst[1] = w1;
        if (m == 0) {
            float g0 = (float)((svt >> 7)  & 31u) * inv;
            float g1 = (float)((svt >> 12) & 31u) * inv;
            float g2 = (float)((svt >> 17) & 31u) * inv;
            float g3 = (float)((svt >> 22) & 31u) * inv;
            float g4 = (float)((svt >> 27) & 31u) * inv;
            uint4 wo;
            wo.x = pack2(g0, g1); wo.y = pack2(g2, g3);
            wo.z = pack2(g4, 0.f); wo.w = 0u;
            *reinterpret_cast<uint4*>(&sA[slot][r][128]) = wo;
        }
    };

    auto build_self = [&](int slot) {
        const uint4* p = reinterpret_cast<const uint4*>(xb + (size_t)n * 128 + m * 16);
        uint4 s0 = p[0], s1 = p[1];
        uint4* dst = reinterpret_cast<uint4*>(&sA[slot][r][m * 16]);
        dst[0] = s0;
        dst[1] = s1;
        if (m == 0) {
            uint4 wo;
            wo.x = pack2((float)(ntS == 0), (float)(ntS == 1));
            wo.y = pack2((float)(ntS == 2), (float)(ntS == 3));
            wo.z = pack2((float)(ntS == 4), 0.f);
            wo.w = 0u;
            *reinterpret_cast<uint4*>(&sA[slot][r][128]) = wo;
        }
    };

    // ---------------- consumer state (waves 4-7) ----------------
    const int p   = wid - 4;            // cb pair: cbs 2p, 2p+1
    const int arl = lane & 15;
    const int g8  = (lane >> 4) << 3;
    f32x4 acc00 = {0.f,0.f,0.f,0.f}, acc01 = {0.f,0.f,0.f,0.f};
    f32x4 acc10 = {0.f,0.f,0.f,0.f}, acc11 = {0.f,0.f,0.f,0.f};

    // ---- prologue: builders make tile 0 -> slot 0 ----
    if (!consumer) build_tile(0, 0);
    __syncthreads();

    // ---- pipelined phases: consume tile t | build tile t+1 ----
    #pragma unroll
    for (int t = 0; t < 7; ++t) {
        if (consumer) {
            const int slot = t & 1;
            #pragma unroll
            for (int kc = 0; kc < 5; ++kc) {
                short8 b0 = *reinterpret_cast<const short8*>(
                    wb + ((((t * 5 + kc) * 8 + 2 * p) << 6) + lane) * 8);
                short8 b1 = *reinterpret_cast<const short8*>(
                    wb + ((((t * 5 + kc) * 8 + 2 * p + 1) << 6) + lane) * 8);
                short8 a0 = *reinterpret_cast<const short8*>(
                    &sA[slot][arl][kc * 32 + g8]);
                short8 a1 = *reinterpret_cast<const short8*>(
                    &sA[slot][16 + arl][kc * 32 + g8]);
                acc00 = __builtin_amdgcn_mfma_f32_16x16x32_bf16(a0, b0, acc00, 0, 0, 0);
                acc01 = __builtin_amdgcn_mfma_f32_16x16x32_bf16(a0, b1, acc01, 0, 0, 0);
                acc10 = __builtin_amdgcn_mfma_f32_16x16x32_bf16(a1, b0, acc10, 0, 0, 0);
                acc11 = __builtin_amdgcn_mfma_f32_16x16x32_bf16(a1, b1, acc11, 0, 0, 0);
            }
        } else {
            if (t < 5)       build_tile(t + 1, (t + 1) & 1);
            else if (t == 5) build_self(0);     // tile 6 -> slot 0
        }
        if (t < 6) __syncthreads();
    }

    // ---- epilogue (consumers only): C/D col = lane&15, row = (lane>>4)*4+reg ----
    if (consumer) {
        const int ro = (lane >> 4) << 2;
        const int oc = (2 * p) * 16 + (lane & 15);
        #pragma unroll
        for (int rr = 0; rr < 4; ++rr) {
            out[(size_t)(n0 + ro + rr) * 128 + oc]           = acc00[rr];
            out[(size_t)(n0 + ro + rr) * 128 + oc + 16]      = acc01[rr];
            out[(size_t)(n0 + 16 + ro + rr) * 128 + oc]      = acc10[rr];
            out[(size_t)(n0 + 16 + ro + rr) * 128 + oc + 16] = acc11[rr];
        }
    }
}

// ---------------- launch ----------------

extern "C" void kernel_launch(void* const* d_in, const int* in_sizes, int n_in,
                              void* d_out, int out_size, void* d_ws, size_t ws_size,
                              hipStream_t stream) {
    const float* x     = (const float*)d_in[0];
    const int*   eidx  = (const int*)d_in[1];
    const int*   etype = (const int*)d_in[2];
    const int*   ntype = (const int*)d_in[3];
    const float* W     = (const float*)d_in[4];
    float* out = (float*)d_out;

    // ws: xb (65537 rows) 16777472 | wb 286720 | seg32 1835008 | scol 11010048
    unsigned short* xb    = (unsigned short*)d_ws;
    unsigned short* wb    = (unsigned short*)((char*)d_ws + 16777472);
    unsigned*       seg32 = (unsigned*)((char*)d_ws + 17064192);
    unsigned short* scol  = (unsigned short*)((char*)d_ws + 18899200);

    hipMemsetAsync(seg32, 0, NSEG * sizeof(unsigned), stream);
    k_big <<<4096,         256, 0, stream>>>(x, eidx, etype, ntype, W, xb, wb, seg32, scol);
    k_main<<<N_NODES / 32, 512, 0, stream>>>(xb, ntype, seg32, scol, wb, out);
}